// Round 9
// baseline (1683.889 us; speedup 1.0000x reference)
//
#include <hip/hip_runtime.h>
#include <hip/hip_bf16.h>
#include <hip/hip_fp16.h>

#define N_NODES 100000
#define N_EDGES 1600000
#define KITER   10
#define ALPHA   0.1f
#define MX      256   // input feature dim
#define MH      64    // hidden dim
#define MY      64    // output feature dim

#define N_SBLK ((N_NODES + 255) / 256)   // 391 scan blocks
#define PCH    16                         // features per chunk (fp16)
#define NCH    4                          // chunks (4*16 = 64)
#define NBLK_P ((N_NODES + 3) / 4)        // 25000 node-tiles per pass

typedef __attribute__((ext_vector_type(8))) short bf16x8;   // 8 bf16 = 4 VGPRs
typedef __attribute__((ext_vector_type(4))) float f32x4;

static __device__ __forceinline__ float us2f(unsigned short u) {
    union { unsigned int i; float f; } v; v.i = ((unsigned int)u) << 16; return v.f;
}
static __device__ __forceinline__ unsigned short f2us(float f) {
    union { float f; unsigned int i; } v; v.f = f;
    unsigned int x = v.i;
    unsigned int r = (x + 0x7fffu + ((x >> 16) & 1u)) >> 16;  // RNE
    return (unsigned short)r;
}
static __device__ __forceinline__ float loadf(const void* p, size_t i, int f32) {
    return f32 ? ((const float*)p)[i] : us2f(((const unsigned short*)p)[i]);
}

// ---------------------------------------------------------------------------
// Runtime dtype detection.
// flags[0] = 1 if float inputs are fp32 (else packed bf16)
// flags[1] = 1 if edge_index is int64 (else int32)
// ---------------------------------------------------------------------------
__global__ __launch_bounds__(256) void detect_kernel(
    const void* __restrict__ x, const int* __restrict__ ei, int* __restrict__ flags)
{
    __shared__ int cnt_weird, cnt_nz_odd;
    const int tid = threadIdx.x;
    if (tid == 0) { cnt_weird = 0; cnt_nz_odd = 0; }
    __syncthreads();
    const unsigned short* xu = (const unsigned short*)x;
    int w = 0, nz = 0;
    for (int i = tid; i < 512; i += 256) {
        unsigned e = (xu[2 * i] >> 7) & 0xFFu;     // exponent field if bf16
        if (e != 0u && (e < 105u || e > 141u)) w++;
        if (ei[2 * i + 1] != 0) nz++;              // high word if int64
    }
    atomicAdd(&cnt_weird, w);
    atomicAdd(&cnt_nz_odd, nz);
    __syncthreads();
    if (tid == 0) {
        flags[0] = (cnt_weird > 64) ? 1 : 0;
        flags[1] = (cnt_nz_odd == 0) ? 1 : 0;
    }
}

// ---------------------------------------------------------------------------
// MFMA MLP v5 = mlp3 structure (low LDS, B-frags from global/L1, ~58% occ)
// + x-row preloaded into registers (8 independent loads -> ILP)
// + blocked-chunk fp16 output (4 chunks of [N][16]).
// ---------------------------------------------------------------------------
#define H1S_LD 72
__global__ __launch_bounds__(256) void mlp5_kernel(
    const void* __restrict__ x,
    const void* __restrict__ W1,
    const void* __restrict__ b1,
    const void* __restrict__ W2,
    const void* __restrict__ b2,
    const int* __restrict__ flags,
    float* __restrict__ h0,          // fp32 [node][64] out (tier<2), may be null
    __half* __restrict__ h0h)        // fp16 blocked out (tier2), may be null
{
    __shared__ unsigned short Hs[4][16][H1S_LD];   // 9.2 KB, per-wave slices

    const int f32  = flags[0];
    const int tid  = threadIdx.x;
    const int wave = tid >> 6;
    const int lane = tid & 63;
    const int l16  = lane & 15;
    const int quad = lane >> 4;

    const int gw   = blockIdx.x * 4 + wave;        // global wave id
    const int base = gw * 16;
    if (base >= N_NODES) return;
    const int arow = min(base + l16, N_NODES - 1); // clamped load row

    const unsigned short* xu  = (const unsigned short*)x;
    const float*          xf  = (const float*)x;
    const unsigned short* W1u = (const unsigned short*)W1;
    const float*          W1f = (const float*)W1;
    const unsigned short* W2u = (const unsigned short*)W2;
    const float*          W2f = (const float*)W2;

    // ---- preload x row fragments into registers (8 independent loads) ----
    bf16x8 xa[8];
    if (f32) {
        #pragma unroll
        for (int s = 0; s < 8; ++s) {
            const float* p = xf + (size_t)arow * MX + s * 32 + quad * 8;
            float4 u = *(const float4*)p, v = *(const float4*)(p + 4);
            bf16x8 a;
            a[0]=(short)f2us(u.x); a[1]=(short)f2us(u.y); a[2]=(short)f2us(u.z); a[3]=(short)f2us(u.w);
            a[4]=(short)f2us(v.x); a[5]=(short)f2us(v.y); a[6]=(short)f2us(v.z); a[7]=(short)f2us(v.w);
            xa[s] = a;
        }
    } else {
        #pragma unroll
        for (int s = 0; s < 8; ++s)
            xa[s] = *(const bf16x8*)(xu + (size_t)arow * MX + s * 32 + quad * 8);
    }

    // ---- layer 1: C1[16,64] = X[16,256] * W1^T (A regs, B global/L1) ----
    f32x4 acc[4] = {{0,0,0,0},{0,0,0,0},{0,0,0,0},{0,0,0,0}};
    #pragma unroll
    for (int s = 0; s < 8; ++s) {
        const int k0 = s * 32 + quad * 8;
        #pragma unroll
        for (int cb = 0; cb < 4; ++cb) {
            const int brow = cb * 16 + l16;
            bf16x8 b;
            if (f32) {
                const float* p = W1f + (size_t)brow * MX + k0;
                float4 u = *(const float4*)p, v = *(const float4*)(p + 4);
                b[0]=(short)f2us(u.x); b[1]=(short)f2us(u.y); b[2]=(short)f2us(u.z); b[3]=(short)f2us(u.w);
                b[4]=(short)f2us(v.x); b[5]=(short)f2us(v.y); b[6]=(short)f2us(v.z); b[7]=(short)f2us(v.w);
            } else {
                b = *(const bf16x8*)(W1u + (size_t)brow * MX + k0);
            }
            acc[cb] = __builtin_amdgcn_mfma_f32_16x16x32_bf16(xa[s], b, acc[cb], 0, 0, 0);
        }
    }
    // bias + relu -> per-wave LDS tile (C layout -> A layout relayout)
    #pragma unroll
    for (int cb = 0; cb < 4; ++cb) {
        #pragma unroll
        for (int reg = 0; reg < 4; ++reg) {
            const int row = quad * 4 + reg;
            const int col = cb * 16 + l16;
            float v = fmaxf(acc[cb][reg] + loadf(b1, col, f32), 0.0f);
            Hs[wave][row][col] = f2us(v);
        }
    }
    // ---- layer 2: C2[16,64] = relu(C1)[16,64] * W2^T ----
    f32x4 acc2[4] = {{0,0,0,0},{0,0,0,0},{0,0,0,0},{0,0,0,0}};
    #pragma unroll
    for (int s = 0; s < 2; ++s) {
        const int k0 = s * 32 + quad * 8;
        bf16x8 a = *(const bf16x8*)&Hs[wave][l16][k0];
        #pragma unroll
        for (int cb = 0; cb < 4; ++cb) {
            const int brow = cb * 16 + l16;
            bf16x8 b;
            if (f32) {
                const float* p = W2f + (size_t)brow * MH + k0;
                float4 u = *(const float4*)p, v = *(const float4*)(p + 4);
                b[0]=(short)f2us(u.x); b[1]=(short)f2us(u.y); b[2]=(short)f2us(u.z); b[3]=(short)f2us(u.w);
                b[4]=(short)f2us(v.x); b[5]=(short)f2us(v.y); b[6]=(short)f2us(v.z); b[7]=(short)f2us(v.w);
            } else {
                b = *(const bf16x8*)(W2u + (size_t)brow * MH + k0);
            }
            acc2[cb] = __builtin_amdgcn_mfma_f32_16x16x32_bf16(a, b, acc2[cb], 0, 0, 0);
        }
    }
    // C2 + b2 back into the per-wave tile as fp16 bits
    #pragma unroll
    for (int cb = 0; cb < 4; ++cb) {
        #pragma unroll
        for (int reg = 0; reg < 4; ++reg) {
            const int row = quad * 4 + reg;
            const int col = cb * 16 + l16;
            float v = acc2[cb][reg] + loadf(b2, col, f32);
            Hs[wave][row][col] = __half_as_ushort(__float2half(v));
        }
    }
    // blocked fp16 output: 2 rows per instruction, 32-B chunk segments
    if (h0h) {
        #pragma unroll
        for (int r2 = 0; r2 < 16; r2 += 2) {
            const int r  = r2 + (lane >> 5);
            const int gr = base + r;
            const int c  = (lane & 31) >> 3;     // chunk 0..3
            const int i8 = lane & 7;             // half2 idx within chunk
            if (gr < N_NODES) {
                const unsigned int u = *(const unsigned int*)&Hs[wave][r][2 * (lane & 31)];
                *((unsigned int*)((__half*)h0h + ((size_t)c * N_NODES + gr) * PCH) + i8) = u;
            }
        }
    }
    if (h0) {
        #pragma unroll 4
        for (int r = 0; r < 16; ++r) {
            const int gr = base + r;
            if (gr < N_NODES)
                h0[(size_t)gr * MY + lane] =
                    __half2float(__ushort_as_half(Hs[wave][r][lane]));
        }
    }
}

// ---------------------------------------------------------------------------
__global__ __launch_bounds__(256) void zero_deg_kernel(int* __restrict__ deg) {
    int i = blockIdx.x * 256 + threadIdx.x;
    if (i < N_NODES) deg[i] = 0;
}

__global__ __launch_bounds__(256) void deg_kernel(
    const int* __restrict__ ei, const int* __restrict__ flags, int* __restrict__ deg)
{
    int e = blockIdx.x * 256 + threadIdx.x;
    if (e < N_EDGES) {
        int d = flags[1] ? ei[2 * (N_EDGES + e)] : ei[N_EDGES + e];
        atomicAdd(&deg[d], 1);
    }
}

__global__ __launch_bounds__(256) void dinv_kernel(
    const int* __restrict__ deg, float* __restrict__ dinv)
{
    int i = blockIdx.x * 256 + threadIdx.x;
    if (i < N_NODES) dinv[i] = rsqrtf((float)(deg[i] + 1)); // +1 self loop
}

// ---- hierarchical exclusive scan: deg -> rowptr ---------------------------
__global__ __launch_bounds__(256) void scan_partial_kernel(
    const int* __restrict__ deg, int* __restrict__ bsum)
{
    __shared__ int red[256];
    const int b = blockIdx.x;
    const int i = b * 256 + threadIdx.x;
    red[threadIdx.x] = (i < N_NODES) ? deg[i] : 0;
    __syncthreads();
    for (int s = 128; s > 0; s >>= 1) {
        if (threadIdx.x < s) red[threadIdx.x] += red[threadIdx.x + s];
        __syncthreads();
    }
    if (threadIdx.x == 0) bsum[b] = red[0];
}

__global__ __launch_bounds__(256) void scan_block_kernel(
    const int* __restrict__ bsum, int* __restrict__ boff)
{
    __shared__ int vals[N_SBLK];
    for (int i = threadIdx.x; i < N_SBLK; i += 256) vals[i] = bsum[i];
    __syncthreads();
    if (threadIdx.x == 0) {
        int run = 0;
        for (int i = 0; i < N_SBLK; ++i) { int v = vals[i]; vals[i] = run; run += v; }
    }
    __syncthreads();
    for (int i = threadIdx.x; i < N_SBLK; i += 256) boff[i] = vals[i];
}

__global__ __launch_bounds__(256) void rowptr_kernel(
    const int* __restrict__ deg, const int* __restrict__ boff,
    int* __restrict__ rowptr, int* __restrict__ fill)
{
    __shared__ int sc[256];
    const int b = blockIdx.x;
    const int i = b * 256 + threadIdx.x;
    const int v = (i < N_NODES) ? deg[i] : 0;
    sc[threadIdx.x] = v;
    __syncthreads();
    #pragma unroll
    for (int s = 1; s < 256; s <<= 1) {       // Hillis-Steele inclusive
        int t = (threadIdx.x >= s) ? sc[threadIdx.x - s] : 0;
        __syncthreads();
        sc[threadIdx.x] += t;
        __syncthreads();
    }
    const int incl = sc[threadIdx.x];
    if (i < N_NODES) { rowptr[i] = boff[b] + incl - v; fill[i] = 0; }
    if (i == N_NODES - 1) rowptr[N_NODES] = boff[b] + incl;
}

// Scatter edges into dst-sorted CSR: csr[pos] = {src, (1-a)*dinv[s]*dinv[d]}
__global__ __launch_bounds__(256) void fill_kernel(
    const int* __restrict__ ei, const int* __restrict__ flags,
    const float* __restrict__ dinv, const int* __restrict__ rowptr,
    int* __restrict__ fill, int2* __restrict__ csr)
{
    int e = blockIdx.x * 256 + threadIdx.x;
    if (e >= N_EDGES) return;
    int s, d;
    if (flags[1]) { s = ei[2 * e]; d = ei[2 * (N_EDGES + e)]; }
    else          { s = ei[e];     d = ei[N_EDGES + e]; }
    float w = (1.0f - ALPHA) * dinv[s] * dinv[d];
    int pos = rowptr[d] + atomicAdd(&fill[d], 1);
    csr[pos] = make_int2(s, __float_as_int(w));
}

// ---------------------------------------------------------------------------
// Blocked-feature fp16 pull. h stored as 4 chunks of [N][16] (3.2 MB each ->
// per-XCD-L2 resident). Grid = 4 passes x 25000 node-tiles; in-order dispatch
// keeps ~one pass (one chunk) active at a time.
// Lanes: 8 lanes/edge (half2 each), 8 edge slots, 16 edges in flight.
// ---------------------------------------------------------------------------
__global__ __launch_bounds__(256) void pull16c_kernel(
    const int* __restrict__ rowptr, const int2* __restrict__ csr,
    const float* __restrict__ dinv,
    const __half* __restrict__ h0h, const __half* __restrict__ hin,
    __half* __restrict__ hout,
    const int* __restrict__ flags, void* __restrict__ outp, int write_out)
{
    const int wave  = threadIdx.x >> 6;
    const int lane  = threadIdx.x & 63;
    const int pass  = blockIdx.x / NBLK_P;
    const int tile  = blockIdx.x - pass * NBLK_P;
    const int node  = tile * 4 + wave;
    if (node >= N_NODES) return;
    const int ledge = lane >> 3;     // edge slot 0..7
    const int lfeat = lane & 7;      // half2 index within chunk

    const __half* hc  = hin + (size_t)pass * N_NODES * PCH;
    const __half* h0c = h0h + (size_t)pass * N_NODES * PCH;

    int p = rowptr[node];
    const int end = rowptr[node + 1];
    float ax = 0.0f, ay = 0.0f;
    for (; p + 16 <= end; p += 16) {
        int2 e0 = csr[p + ledge];
        int2 e1 = csr[p + 8 + ledge];
        __half2 v0 = *((const __half2*)(hc + (size_t)e0.x * PCH) + lfeat);
        __half2 v1 = *((const __half2*)(hc + (size_t)e1.x * PCH) + lfeat);
        float w0 = __int_as_float(e0.y), w1 = __int_as_float(e1.y);
        float2 f0 = __half22float2(v0), f1 = __half22float2(v1);
        ax += w0 * f0.x + w1 * f1.x;
        ay += w0 * f0.y + w1 * f1.y;
    }
    for (; p < end; p += 8) {
        const int idx = p + ledge;
        if (idx < end) {
            int2 e = csr[idx];
            __half2 v = *((const __half2*)(hc + (size_t)e.x * PCH) + lfeat);
            float w = __int_as_float(e.y);
            float2 f = __half22float2(v);
            ax += w * f.x; ay += w * f.y;
        }
    }
    // reduce over the 8 edge slots (lane bits 3..5)
    ax += __shfl_xor(ax, 8);  ay += __shfl_xor(ay, 8);
    ax += __shfl_xor(ax, 16); ay += __shfl_xor(ay, 16);
    ax += __shfl_xor(ax, 32); ay += __shfl_xor(ay, 32);

    if (ledge == 0) {
        const float dv = dinv[node];
        const float ws = (1.0f - ALPHA) * dv * dv;
        float2 hv  = __half22float2(*((const __half2*)(hc  + (size_t)node * PCH) + lfeat));
        float2 h0v = __half22float2(*((const __half2*)(h0c + (size_t)node * PCH) + lfeat));
        float rx = ax + ws * hv.x + ALPHA * h0v.x;
        float ry = ay + ws * hv.y + ALPHA * h0v.y;
        if (write_out) {
            if (flags[0]) {
                ((float2*)outp)[(size_t)node * 32 + pass * 8 + lfeat] = make_float2(rx, ry);
            } else {
                ((unsigned int*)outp)[(size_t)node * 32 + pass * 8 + lfeat] =
                    (unsigned int)f2us(rx) | ((unsigned int)f2us(ry) << 16);
            }
        } else {
            *((__half2*)(hout + ((size_t)pass * N_NODES + node) * PCH) + lfeat) =
                __floats2half2_rn(rx, ry);
        }
    }
}

// fp32-h pull (mid-tier fallback)
__global__ __launch_bounds__(256) void pull_kernel(
    const int* __restrict__ rowptr, const int2* __restrict__ csr,
    const float* __restrict__ dinv,
    const float* __restrict__ h0, const float* __restrict__ hin,
    float* __restrict__ hout,
    const int* __restrict__ flags, void* __restrict__ outp, int write_out)
{
    const int lane = threadIdx.x & 63;
    const int node = blockIdx.x * 4 + (threadIdx.x >> 6);
    if (node >= N_NODES) return;
    int p   = rowptr[node];
    const int end = rowptr[node + 1];
    float acc = 0.0f;
    for (; p + 3 < end; p += 4) {
        int2 e0 = csr[p], e1 = csr[p + 1], e2 = csr[p + 2], e3 = csr[p + 3];
        float v0 = hin[(size_t)e0.x * MY + lane];
        float v1 = hin[(size_t)e1.x * MY + lane];
        float v2 = hin[(size_t)e2.x * MY + lane];
        float v3 = hin[(size_t)e3.x * MY + lane];
        acc += __int_as_float(e0.y) * v0;
        acc += __int_as_float(e1.y) * v1;
        acc += __int_as_float(e2.y) * v2;
        acc += __int_as_float(e3.y) * v3;
    }
    for (; p < end; ++p) {
        int2 e = csr[p];
        acc += __int_as_float(e.y) * hin[(size_t)e.x * MY + lane];
    }
    const size_t o = (size_t)node * MY + lane;
    float dv = dinv[node];
    float r = acc + (1.0f - ALPHA) * dv * dv * hin[o] + ALPHA * h0[o];
    if (write_out) {
        if (flags[0]) ((float*)outp)[o] = r;
        else          ((unsigned short*)outp)[o] = f2us(r);
    } else {
        hout[o] = r;
    }
}

// ---- fallback (atomic push) kernels, used only if ws too small ------------
__global__ __launch_bounds__(256) void self_kernel(
    const float4* __restrict__ h0, const float4* __restrict__ hin,
    const float* __restrict__ dinv, float4* __restrict__ hout)
{
    int idx = blockIdx.x * 256 + threadIdx.x;
    if (idx >= N_NODES * (MY / 4)) return;
    int node = idx / (MY / 4);
    float d = dinv[node];
    float w = (1.0f - ALPHA) * d * d;
    float4 a = h0[idx], b = hin[idx];
    float4 o;
    o.x = ALPHA * a.x + w * b.x;
    o.y = ALPHA * a.y + w * b.y;
    o.z = ALPHA * a.z + w * b.z;
    o.w = ALPHA * a.w + w * b.w;
    hout[idx] = o;
}

__global__ __launch_bounds__(256) void edge_kernel(
    const int* __restrict__ ei, const int* __restrict__ flags,
    const float* __restrict__ dinv,
    const float* __restrict__ hin, float* __restrict__ hout)
{
    int lane = threadIdx.x & 63;
    int e = blockIdx.x * 4 + (threadIdx.x >> 6);
    if (e >= N_EDGES) return;
    int s, d;
    if (flags[1]) { s = ei[2 * e]; d = ei[2 * (N_EDGES + e)]; }
    else          { s = ei[e];     d = ei[N_EDGES + e]; }
    float w = (1.0f - ALPHA) * dinv[s] * dinv[d];
    atomicAdd(&hout[(size_t)d * MY + lane], w * hin[(size_t)s * MY + lane]);
}

__global__ __launch_bounds__(256) void out_kernel(
    const float* __restrict__ h, void* __restrict__ out, const int* __restrict__ flags)
{
    int idx = blockIdx.x * 256 + threadIdx.x;
    if (idx < N_NODES * MY) {
        float v = h[idx];
        if (flags[0]) ((float*)out)[idx] = v;
        else          ((unsigned short*)out)[idx] = f2us(v);
    }
}

// ---------------------------------------------------------------------------
extern "C" void kernel_launch(void* const* d_in, const int* in_sizes, int n_in,
                              void* d_out, int out_size, void* d_ws, size_t ws_size,
                              hipStream_t stream)
{
    const void* x  = d_in[0];
    const void* W1 = d_in[1];
    const void* b1 = d_in[2];
    const void* W2 = d_in[3];
    const void* b2 = d_in[4];
    const int*  ei = (const int*)d_in[5];

    const size_t HN = (size_t)N_NODES * MY;    // 6.4M elements
    char* base = (char*)d_ws;
    int*    flags  = (int*)base;                    base += 256;
    float*  h0     = (float*)base;                  base += HN * 4;
    float*  hA32   = (float*)base;                  base += HN * 4;
    float*  hB32   = (float*)base;                  base += HN * 4;
    float*  dinv   = (float*)base;                  base += (size_t)N_NODES * 4;
    int*    deg    = (int*)base;                    base += (size_t)N_NODES * 4;
    int*    rowptr = (int*)base;                    base += ((size_t)N_NODES + 4) * 4;
    int*    fill   = (int*)base;                    base += (size_t)N_NODES * 4;
    int*    bsum   = (int*)base;                    base += ((size_t)N_SBLK + 4) * 4;
    int*    boff   = (int*)base;                    base += ((size_t)N_SBLK + 4) * 4;
    int2*   csr    = (int2*)base;                   base += (size_t)N_EDGES * 8;
    const size_t need_csr32 = (size_t)(base - (char*)d_ws);
    __half* h0h    = (__half*)base;                 base += HN * 2;
    __half* hAh    = (__half*)base;                 base += HN * 2;
    __half* hBh    = (__half*)base;                 base += HN * 2;
    const size_t need_fp16 = (size_t)(base - (char*)d_ws);
    const int tier = (ws_size >= need_fp16) ? 2 : (ws_size >= need_csr32 ? 1 : 0);

    detect_kernel<<<1, 256, 0, stream>>>(x, ei, flags);
    zero_deg_kernel<<<(N_NODES + 255) / 256, 256, 0, stream>>>(deg);
    mlp5_kernel<<<((N_NODES + 15) / 16 + 3) / 4, 256, 0, stream>>>(
        x, W1, b1, W2, b2, flags,
        tier == 2 ? (float*)nullptr : h0,
        tier == 2 ? h0h : (__half*)nullptr);
    deg_kernel<<<(N_EDGES + 255) / 256, 256, 0, stream>>>(ei, flags, deg);
    dinv_kernel<<<(N_NODES + 255) / 256, 256, 0, stream>>>(deg, dinv);

    if (tier >= 1) {
        scan_partial_kernel<<<N_SBLK, 256, 0, stream>>>(deg, bsum);
        scan_block_kernel<<<1, 256, 0, stream>>>(bsum, boff);
        rowptr_kernel<<<N_SBLK, 256, 0, stream>>>(deg, boff, rowptr, fill);
        fill_kernel<<<(N_EDGES + 255) / 256, 256, 0, stream>>>(
            ei, flags, dinv, rowptr, fill, csr);
    }

    if (tier == 2) {
        const __half* hin = h0h;
        __half* hout = hAh;
        for (int k = 0; k < KITER; ++k) {
            int last = (k == KITER - 1) ? 1 : 0;
            pull16c_kernel<<<NCH * NBLK_P, 256, 0, stream>>>(
                rowptr, csr, dinv, h0h, hin, hout, flags, d_out, last);
            hin = hout;
            hout = (hout == hAh) ? hBh : hAh;
        }
    } else if (tier == 1) {
        const float* hin = h0;
        float* hout = hA32;
        for (int k = 0; k < KITER; ++k) {
            int last = (k == KITER - 1) ? 1 : 0;
            pull_kernel<<<(N_NODES + 3) / 4, 256, 0, stream>>>(
                rowptr, csr, dinv, h0, hin, hout, flags, d_out, last);
            hin = hout;
            hout = (hout == hA32) ? hB32 : hA32;
        }
    } else {
        const float* hin = h0;
        float* hout = hA32;
        const int n_f4 = N_NODES * (MY / 4);
        for (int k = 0; k < KITER; ++k) {
            self_kernel<<<(n_f4 + 255) / 256, 256, 0, stream>>>(
                (const float4*)h0, (const float4*)hin, dinv, (float4*)hout);
            edge_kernel<<<(N_EDGES + 3) / 4, 256, 0, stream>>>(ei, flags, dinv, hin, hout);
            hin = hout;
            hout = (hout == hA32) ? hB32 : hA32;
        }
        out_kernel<<<(N_NODES * MY + 255) / 256, 256, 0, stream>>>(hin, d_out, flags);
    }
}